// Round 10
// baseline (9703.916 us; speedup 1.0000x reference)
//
#include <hip/hip_runtime.h>

// ROUND 10 — d_out is FLOAT32 (reference output dtype), not bf16.
// Same verified pipeline as R4: dict-order inputs, h-major concat, out=cat@Wp^T+bp.

#define NB 4
#define NT 2048
#define NC 1024
#define NH 16
#define NHD 64
#define BH (NB * NH)            // 64
typedef unsigned short ushort_t;
#define SLAB ((size_t)NT * (size_t)NT)

__device__ __forceinline__ ushort_t f2bf(float f) {
    unsigned int x = __float_as_uint(f);
    x += 0x7fffu + ((x >> 16) & 1u);   // RTNE; values finite
    return (ushort_t)(x >> 16);
}
__device__ __forceinline__ float bf2f(ushort_t u) {
    return __uint_as_float(((unsigned int)u) << 16);
}

// ---- K1: QKV projection, one output element per thread ----------------------
// q/k/v[bh,t,d] = sum_c x[b,t,c] * W[h,c,d]   (bf16 staging in ws)
__global__ __launch_bounds__(256) void k_qkv(
    const float* __restrict__ x, const float* __restrict__ Wq,
    const float* __restrict__ Wk, const float* __restrict__ Wv,
    ushort_t* __restrict__ q, ushort_t* __restrict__ k, ushort_t* __restrict__ v)
{
    const int tid = threadIdx.x;
    const int r = tid >> 6, d = tid & 63;
    const int t = blockIdx.x * 4 + r;
    const int bh = blockIdx.y;
    const int b = bh >> 4, h = bh & 15;
    const int sel = blockIdx.z;
    const float* W = (sel == 0 ? Wq : (sel == 1 ? Wk : Wv)) + (size_t)h * NC * NHD + d;
    const float* xrow = x + ((size_t)b * NT + t) * NC;
    float a0 = 0.f, a1 = 0.f, a2 = 0.f, a3 = 0.f;
    for (int c = 0; c < NC; c += 4) {
        a0 = fmaf(xrow[c + 0], W[(size_t)(c + 0) * NHD], a0);
        a1 = fmaf(xrow[c + 1], W[(size_t)(c + 1) * NHD], a1);
        a2 = fmaf(xrow[c + 2], W[(size_t)(c + 2) * NHD], a2);
        a3 = fmaf(xrow[c + 3], W[(size_t)(c + 3) * NHD], a3);
    }
    const float acc = (a0 + a1) + (a2 + a3);
    ushort_t* outp = (sel == 0 ? q : (sel == 1 ? k : v));
    outp[((size_t)bh * NT + t) * NHD + d] = f2bf(acc);
}

// ---- K2: one block per (bh, row i): e = exp(qj.ki/32) for j<=i, row sum -----
__global__ __launch_bounds__(256) void k_scores(
    const ushort_t* __restrict__ q, const ushort_t* __restrict__ k,
    float* __restrict__ w, float* __restrict__ l_arr)
{
    __shared__ float kf[NHD];
    __shared__ float red[4];
    const int i = blockIdx.x;
    const int bh = blockIdx.y;
    const int tid = threadIdx.x;
    const ushort_t* kb = k + ((size_t)bh * NT + i) * NHD;
    if (tid < NHD) kf[tid] = bf2f(kb[tid]);
    __syncthreads();
    float* wrow = w + (size_t)bh * SLAB + (size_t)i * NT;
    const ushort_t* qb = q + (size_t)bh * NT * NHD;
    float lsum = 0.f;
    for (int j0 = 0; j0 < NT; j0 += 256) {
        const int j = j0 + tid;
        float e = 0.f;
        if (j <= i) {
            const ushort_t* qr = qb + (size_t)j * NHD;
            float s = 0.f;
            for (int d = 0; d < NHD; d += 4) {
                ushort4 u4 = *(const ushort4*)(qr + d);
                s = fmaf(kf[d + 0], bf2f(u4.x), s);
                s = fmaf(kf[d + 1], bf2f(u4.y), s);
                s = fmaf(kf[d + 2], bf2f(u4.z), s);
                s = fmaf(kf[d + 3], bf2f(u4.w), s);
            }
            e = __expf(s * 0.03125f);     // scale = sqrt(C) = 32
            lsum += e;
        }
        wrow[j] = e;                      // f32; exact 0 above diagonal
    }
    for (int off = 32; off > 0; off >>= 1)
        lsum += __shfl_down(lsum, off, 64);
    if ((tid & 63) == 0) red[tid >> 6] = lsum;
    __syncthreads();
    if (tid == 0)
        l_arr[(size_t)bh * NT + i] = (red[0] + red[1]) + (red[2] + red[3]);
}

// ---- K2b: normalize row in place (f32), emit diag ---------------------------
__global__ __launch_bounds__(256) void k_norm(
    float* __restrict__ w, const float* __restrict__ l_arr,
    float* __restrict__ diag)
{
    const int row = blockIdx.x;          // bh*NT + i
    const int i = row & (NT - 1);
    const float linv = 1.0f / l_arr[row];
    float4* wrow = (float4*)(w + (size_t)row * NT);
    const int nc4 = i >> 2;              // last float4 chunk containing j=i
    for (int c = threadIdx.x; c <= nc4; c += 256) {
        float4 u = wrow[c];
        u.x *= linv; u.y *= linv; u.z *= linv; u.w *= linv;
        wrow[c] = u;                      // zeros above diag stay zero
        if (c == nc4) diag[row] = ((float*)&u)[i & 3];
    }
}

// ---- K3: out[b,t,n] = sum_c diag*v (h-major concat) . Wp[n,:] + bp[n] -------
__global__ __launch_bounds__(256) void k_out(
    const ushort_t* __restrict__ v, const float* __restrict__ diag,
    const float* __restrict__ Wp, const float* __restrict__ bpv,
    float* __restrict__ out)
{
    __shared__ float cat[16][NC];       // 64 KB
    const int tid = threadIdx.x;
    const int t0 = (blockIdx.x % (NT / 16)) * 16;
    const int b  = blockIdx.x / (NT / 16);
    for (int r = 0; r < 16; ++r) {
        const int t = t0 + r;
        for (int c0 = 0; c0 < NC; c0 += 256) {
            const int c = c0 + tid;
            const int h = c >> 6, d = c & 63;
            const float dg = diag[(size_t)(b * NH + h) * NT + t];
            cat[r][c] = dg * bf2f(v[((size_t)(b * NH + h) * NT + t) * NHD + d]);
        }
    }
    __syncthreads();
    for (int g = 0; g < 4; ++g) {
        const int n = g * 256 + tid;
        const float* wr = Wp + (size_t)n * NC;     // Wp^T: Wp[n,c]
        const float bias = bpv[n];
        float acc[16];
        #pragma unroll
        for (int r = 0; r < 16; ++r) acc[r] = bias;
        for (int c = 0; c < NC; ++c) {
            const float wv = wr[c];
            #pragma unroll
            for (int r = 0; r < 16; ++r) acc[r] = fmaf(cat[r][c], wv, acc[r]);
        }
        #pragma unroll
        for (int r = 0; r < 16; ++r)
            out[((size_t)b * NT + t0 + r) * NC + n] = acc[r];
    }
}

extern "C" void kernel_launch(void* const* d_in, const int* in_sizes, int n_in,
                              void* d_out, int out_size, void* d_ws, size_t ws_size,
                              hipStream_t stream)
{
    const float* x  = (const float*)d_in[0];
    const float* Wq = (const float*)d_in[1];
    const float* Wk = (const float*)d_in[2];
    const float* Wv = (const float*)d_in[3];
    const float* Wp = (const float*)d_in[4];
    const float* bp = (const float*)d_in[5];

    float* out = (float*)d_out;                      // FLOAT32 outputs
    float* w = out + (size_t)NB * NT * NC;           // weights region (f32)

    ushort_t* qs = (ushort_t*)d_ws;                  // bf16 staging
    ushort_t* ks = qs + (size_t)BH * NT * NHD;
    ushort_t* vs = ks + (size_t)BH * NT * NHD;
    float* l_arr = (float*)(vs + (size_t)BH * NT * NHD);
    float* diag = l_arr + (size_t)BH * NT;

    k_qkv<<<dim3(NT / 4, BH, 3), 256, 0, stream>>>(x, Wq, Wk, Wv, qs, ks, vs);
    k_scores<<<dim3(NT, BH), 256, 0, stream>>>(qs, ks, w, l_arr);
    k_norm<<<BH * NT, 256, 0, stream>>>(w, l_arr, diag);
    k_out<<<NB * (NT / 16), 256, 0, stream>>>(vs, diag, Wp, bp, out);
}

// Round 11
// 1582.398 us; speedup vs baseline: 6.1324x; 6.1324x over previous
//
#include <hip/hip_runtime.h>

// ROUND 11 — same verified dataflow as R10 (PASSED), hot kernels replaced by
// LDS-tiled versions (64x64 block tile, 4x4 microtile, 256 threads).

#define NB 4
#define NT 2048
#define NC 1024
#define NH 16
#define NHD 64
#define BH (NB * NH)            // 64
typedef unsigned short ushort_t;
#define SLAB ((size_t)NT * (size_t)NT)

__device__ __forceinline__ ushort_t f2bf(float f) {
    unsigned int x = __float_as_uint(f);
    x += 0x7fffu + ((x >> 16) & 1u);   // RTNE; values finite
    return (ushort_t)(x >> 16);
}
__device__ __forceinline__ float bf2f(ushort_t u) {
    return __uint_as_float(((unsigned int)u) << 16);
}

// ---- K1: QKV projection GEMM (tiled). x[B,T,C] f32 @ W[H,C,HD] f32 -> bf16 --
// M = 8192 rows (b,t), N = 3072 (sel|h|d; each 64-col tile is one (sel,h)).
__global__ __launch_bounds__(256) void qkv_gemm(
    const float* __restrict__ x, const float* __restrict__ Wq,
    const float* __restrict__ Wk, const float* __restrict__ Wv,
    ushort_t* __restrict__ qo, ushort_t* __restrict__ ko, ushort_t* __restrict__ vo)
{
    __shared__ float xs[32][68];   // xs[k][m] (transposed)
    __shared__ float wsh[32][68];  // wsh[k][n]
    const int n0 = blockIdx.x * 64;
    const int m0 = blockIdx.y * 64;
    const int sel = n0 >> 10;                  // 0=q 1=k 2=v
    const int h = (n0 & 1023) >> 6;
    const float* W = (sel == 0 ? Wq : (sel == 1 ? Wk : Wv)) + (size_t)h * (NC * NHD);
    const int t = threadIdx.x;
    const int ty = t >> 4, tx = t & 15;
    float acc[4][4] = {};
    for (int k0 = 0; k0 < NC; k0 += 32) {
        {   // stage x tile (64 m x 32 k), transpose into LDS
            const int m = t >> 2, kk0 = (t & 3) * 8;
            const float* xp = x + (size_t)(m0 + m) * NC + k0 + kk0;
            float4 u0 = *(const float4*)xp;
            float4 u1 = *(const float4*)(xp + 4);
            xs[kk0 + 0][m] = u0.x; xs[kk0 + 1][m] = u0.y;
            xs[kk0 + 2][m] = u0.z; xs[kk0 + 3][m] = u0.w;
            xs[kk0 + 4][m] = u1.x; xs[kk0 + 5][m] = u1.y;
            xs[kk0 + 6][m] = u1.z; xs[kk0 + 7][m] = u1.w;
        }
        {   // stage W tile (32 k x 64 d)
            const int kk = t >> 3, d0 = (t & 7) * 8;
            const float* wp = W + (size_t)(k0 + kk) * NHD + d0;
            float4 u0 = *(const float4*)wp;
            float4 u1 = *(const float4*)(wp + 4);
            wsh[kk][d0 + 0] = u0.x; wsh[kk][d0 + 1] = u0.y;
            wsh[kk][d0 + 2] = u0.z; wsh[kk][d0 + 3] = u0.w;
            wsh[kk][d0 + 4] = u1.x; wsh[kk][d0 + 5] = u1.y;
            wsh[kk][d0 + 6] = u1.z; wsh[kk][d0 + 7] = u1.w;
        }
        __syncthreads();
        #pragma unroll 8
        for (int kk = 0; kk < 32; ++kk) {
            const float4 af = *(const float4*)&xs[kk][ty * 4];
            const float4 bf = *(const float4*)&wsh[kk][tx * 4];
            const float a[4] = {af.x, af.y, af.z, af.w};
            const float b[4] = {bf.x, bf.y, bf.z, bf.w};
            #pragma unroll
            for (int i = 0; i < 4; ++i)
                #pragma unroll
                for (int j = 0; j < 4; ++j)
                    acc[i][j] = fmaf(a[i], b[j], acc[i][j]);
        }
        __syncthreads();
    }
    ushort_t* outp = (sel == 0 ? qo : (sel == 1 ? ko : vo));
    #pragma unroll
    for (int i = 0; i < 4; ++i) {
        const int bt = m0 + ty * 4 + i;
        const int b = bt >> 11, tt = bt & 2047;
        ushort_t* op = outp + ((size_t)(b * NH + h) * NT + tt) * NHD + tx * 4;
        ushort4 o;
        o.x = f2bf(acc[i][0]); o.y = f2bf(acc[i][1]);
        o.z = f2bf(acc[i][2]); o.w = f2bf(acc[i][3]);
        *(ushort4*)op = o;
    }
}

// ---- K2: scores tiled: e = exp(q_j . k_i / 32) f32 into w, row sums ---------
__global__ __launch_bounds__(256) void attn_scores(
    const ushort_t* __restrict__ q, const ushort_t* __restrict__ k,
    float* __restrict__ w, float* __restrict__ l_arr)
{
    __shared__ float ks[64][68];   // ks[d][i_local]
    __shared__ float qs[64][68];   // qs[d][j_local]
    const int ib = blockIdx.x;     // i-block (64 rows)
    const int bh = blockIdx.y;
    const int t = threadIdx.x;
    const int ty = t >> 4, tx = t & 15;
    const ushort_t* kbase = k + (size_t)bh * (NT * NHD);
    const ushort_t* qbase = q + (size_t)bh * (NT * NHD);
    float* wbase = w + (size_t)bh * SLAB;
    {   // stage k tile transposed (bf16 -> f32)
        const int r = t >> 2, d0 = (t & 3) * 16;
        const ushort_t* kp = kbase + (size_t)(ib * 64 + r) * NHD + d0;
        #pragma unroll
        for (int c = 0; c < 4; ++c) {
            ushort4 u4 = *(const ushort4*)(kp + c * 4);
            ks[d0 + c*4 + 0][r] = bf2f(u4.x); ks[d0 + c*4 + 1][r] = bf2f(u4.y);
            ks[d0 + c*4 + 2][r] = bf2f(u4.z); ks[d0 + c*4 + 3][r] = bf2f(u4.w);
        }
    }
    __syncthreads();
    float l_loc[4] = {0.f, 0.f, 0.f, 0.f};
    for (int jt = 0; jt <= ib; ++jt) {
        {   // stage q tile transposed
            const int r = t >> 2, d0 = (t & 3) * 16;
            const ushort_t* qp = qbase + (size_t)(jt * 64 + r) * NHD + d0;
            #pragma unroll
            for (int c = 0; c < 4; ++c) {
                ushort4 u4 = *(const ushort4*)(qp + c * 4);
                qs[d0 + c*4 + 0][r] = bf2f(u4.x); qs[d0 + c*4 + 1][r] = bf2f(u4.y);
                qs[d0 + c*4 + 2][r] = bf2f(u4.z); qs[d0 + c*4 + 3][r] = bf2f(u4.w);
            }
        }
        __syncthreads();
        float s[4][4] = {};
        #pragma unroll 8
        for (int d = 0; d < 64; ++d) {
            const float4 af = *(const float4*)&ks[d][ty * 4];
            const float4 bf = *(const float4*)&qs[d][tx * 4];
            const float a[4] = {af.x, af.y, af.z, af.w};
            const float bb[4] = {bf.x, bf.y, bf.z, bf.w};
            #pragma unroll
            for (int i = 0; i < 4; ++i)
                #pragma unroll
                for (int j = 0; j < 4; ++j)
                    s[i][j] = fmaf(a[i], bb[j], s[i][j]);
        }
        #pragma unroll
        for (int i = 0; i < 4; ++i) {
            const int gi = ib * 64 + ty * 4 + i;
            float ev[4];
            #pragma unroll
            for (int j = 0; j < 4; ++j) {
                const int gj = jt * 64 + tx * 4 + j;
                float e = __expf(s[i][j] * 0.03125f);   // 1/sqrt(C) = 1/32
                e = (gj <= gi) ? e : 0.0f;
                l_loc[i] += e;
                ev[j] = e;
            }
            *(float4*)&wbase[(size_t)gi * NT + jt * 64 + tx * 4] =
                make_float4(ev[0], ev[1], ev[2], ev[3]);
        }
        __syncthreads();
    }
    // zero-fill above the diagonal block
    const float4 z4 = make_float4(0.f, 0.f, 0.f, 0.f);
    for (int jt = ib + 1; jt < NT / 64; ++jt) {
        #pragma unroll
        for (int i = 0; i < 4; ++i) {
            const int gi = ib * 64 + ty * 4 + i;
            *(float4*)&wbase[(size_t)gi * NT + jt * 64 + tx * 4] = z4;
        }
    }
    // reduce row sums across the 16 tx of each row
    __syncthreads();
    float* lred = &qs[0][0];   // reuse LDS (64 x 16)
    #pragma unroll
    for (int i = 0; i < 4; ++i) lred[(ty * 4 + i) * 16 + tx] = l_loc[i];
    __syncthreads();
    if (t < 64) {
        float sum = 0.f;
        #pragma unroll
        for (int c = 0; c < 16; ++c) sum += lred[t * 16 + c];
        l_arr[(size_t)bh * NT + ib * 64 + t] = sum;
    }
}

// ---- K2b: normalize row in place (f32), emit diag ---------------------------
__global__ __launch_bounds__(256) void k_norm(
    float* __restrict__ w, const float* __restrict__ l_arr,
    float* __restrict__ diag)
{
    const int row = blockIdx.x;          // bh*NT + i
    const int i = row & (NT - 1);
    const float linv = 1.0f / l_arr[row];
    float4* wrow = (float4*)(w + (size_t)row * NT);
    const int nc4 = i >> 2;              // last float4 chunk containing j=i
    for (int c = threadIdx.x; c <= nc4; c += 256) {
        float4 u = wrow[c];
        u.x *= linv; u.y *= linv; u.z *= linv; u.w *= linv;
        wrow[c] = u;
        if (c == nc4) diag[row] = ((float*)&u)[i & 3];
    }
}

// ---- K3: out = (diag*v | h-major concat) @ Wp^T + bp (tiled) ----------------
__global__ __launch_bounds__(256) void out_proj(
    const ushort_t* __restrict__ v, const float* __restrict__ diag,
    const float* __restrict__ Wp, const float* __restrict__ bpv,
    float* __restrict__ out)
{
    __shared__ float as_[32][68];   // cat tile transposed [k][m]
    __shared__ float wsp[32][68];   // Wp^T tile [k][n]
    const int n0 = blockIdx.x * 64;
    const int m0 = blockIdx.y * 64;
    const int t = threadIdx.x;
    const int ty = t >> 4, tx = t & 15;
    float acc[4][4] = {};
    for (int k0 = 0; k0 < NC; k0 += 32) {
        const int h = k0 >> 6, dbase = k0 & 63;
        {   // stage cat = diag * v (v bf16)
            const int m = t >> 2, kk0 = (t & 3) * 8;
            const int bt = m0 + m, b = bt >> 11, tt = bt & 2047;
            const ushort_t* vp = v + ((size_t)(b * NH + h) * NT + tt) * NHD + dbase + kk0;
            const float dg = diag[(size_t)(b * NH + h) * NT + tt];
            uint4 u = *(const uint4*)vp;
            const ushort_t* us = (const ushort_t*)&u;
            #pragma unroll
            for (int j = 0; j < 8; ++j) as_[kk0 + j][m] = bf2f(us[j]) * dg;
        }
        {   // stage Wp^T tile: element (k,n) = Wp[n][k]
            const int n = t >> 2, kk0 = (t & 3) * 8;
            const float* wp = Wp + (size_t)(n0 + n) * NC + k0 + kk0;
            float4 u0 = *(const float4*)wp;
            float4 u1 = *(const float4*)(wp + 4);
            wsp[kk0 + 0][n] = u0.x; wsp[kk0 + 1][n] = u0.y;
            wsp[kk0 + 2][n] = u0.z; wsp[kk0 + 3][n] = u0.w;
            wsp[kk0 + 4][n] = u1.x; wsp[kk0 + 5][n] = u1.y;
            wsp[kk0 + 6][n] = u1.z; wsp[kk0 + 7][n] = u1.w;
        }
        __syncthreads();
        #pragma unroll 8
        for (int kk = 0; kk < 32; ++kk) {
            const float4 af = *(const float4*)&as_[kk][ty * 4];
            const float4 bf = *(const float4*)&wsp[kk][tx * 4];
            const float a[4] = {af.x, af.y, af.z, af.w};
            const float bb[4] = {bf.x, bf.y, bf.z, bf.w};
            #pragma unroll
            for (int i = 0; i < 4; ++i)
                #pragma unroll
                for (int j = 0; j < 4; ++j)
                    acc[i][j] = fmaf(a[i], bb[j], acc[i][j]);
        }
        __syncthreads();
    }
    float bias[4];
    {
        float4 ub = *(const float4*)&bpv[n0 + tx * 4];
        bias[0] = ub.x; bias[1] = ub.y; bias[2] = ub.z; bias[3] = ub.w;
    }
    #pragma unroll
    for (int i = 0; i < 4; ++i) {
        const int bt = m0 + ty * 4 + i;
        *(float4*)&out[(size_t)bt * NC + n0 + tx * 4] =
            make_float4(acc[i][0] + bias[0], acc[i][1] + bias[1],
                        acc[i][2] + bias[2], acc[i][3] + bias[3]);
    }
}

extern "C" void kernel_launch(void* const* d_in, const int* in_sizes, int n_in,
                              void* d_out, int out_size, void* d_ws, size_t ws_size,
                              hipStream_t stream)
{
    const float* x  = (const float*)d_in[0];
    const float* Wq = (const float*)d_in[1];
    const float* Wk = (const float*)d_in[2];
    const float* Wv = (const float*)d_in[3];
    const float* Wp = (const float*)d_in[4];
    const float* bp = (const float*)d_in[5];

    float* out = (float*)d_out;                      // f32 outputs
    float* w = out + (size_t)NB * NT * NC;           // weights region (f32)

    ushort_t* qs = (ushort_t*)d_ws;                  // bf16 staging
    ushort_t* ks = qs + (size_t)BH * NT * NHD;
    ushort_t* vs = ks + (size_t)BH * NT * NHD;
    float* l_arr = (float*)(vs + (size_t)BH * NT * NHD);
    float* diag = l_arr + (size_t)BH * NT;

    qkv_gemm<<<dim3(48, 128), 256, 0, stream>>>(x, Wq, Wk, Wv, qs, ks, vs);
    attn_scores<<<dim3(NT / 64, BH), 256, 0, stream>>>(qs, ks, w, l_arr);
    k_norm<<<BH * NT, 256, 0, stream>>>(w, l_arr, diag);
    out_proj<<<dim3(16, 128), 256, 0, stream>>>(vs, diag, Wp, bp, out);
}

// Round 12
// 1299.117 us; speedup vs baseline: 7.4696x; 1.2181x over previous
//
#include <hip/hip_runtime.h>

// ROUND 12 — MFMA for qkv + scores; norm fused into scores (2-pass recompute).
// Dataflow (verified R10/R11): x,W f32 -> bf16 staging -> q/k/v bf16 ->
// w = softmax(tril(K Q^T/32)) f32 (output 1), diag -> out = (diag*v).Wp^T + bp.

#define NB 4
#define NT 2048
#define NC 1024
#define NH 16
#define NHD 64
#define BH (NB * NH)            // 64
typedef unsigned short ushort_t;
#define SLAB ((size_t)NT * (size_t)NT)

typedef __attribute__((ext_vector_type(8))) short short8;   // 8 bf16 = 4 VGPR
typedef __attribute__((ext_vector_type(4))) float f32x4;

__device__ __forceinline__ ushort_t f2bf(float f) {
    unsigned int x = __float_as_uint(f);
    x += 0x7fffu + ((x >> 16) & 1u);   // RTNE; values finite
    return (ushort_t)(x >> 16);
}
__device__ __forceinline__ float bf2f(ushort_t u) {
    return __uint_as_float(((unsigned int)u) << 16);
}

// ---- P1: x f32 -> xbf bf16 --------------------------------------------------
__global__ __launch_bounds__(256) void cvt_x(
    const float* __restrict__ x, ushort_t* __restrict__ xbf)
{
    const size_t o = ((size_t)blockIdx.x * 256 + threadIdx.x) * 4;
    float4 u = *(const float4*)(x + o);
    ushort4 v;
    v.x = f2bf(u.x); v.y = f2bf(u.y); v.z = f2bf(u.z); v.w = f2bf(u.w);
    *(ushort4*)(xbf + o) = v;
}

// ---- P2: W[sel][h][c][d] f32 -> Wt[sel][h][d][c] bf16 (coalesced writes) ----
__global__ __launch_bounds__(256) void cvt_w(
    const float* __restrict__ Wq, const float* __restrict__ Wk,
    const float* __restrict__ Wv, ushort_t* __restrict__ Wt)
{
    const int o = blockIdx.x * 256 + threadIdx.x;    // < 3*16*64*1024
    const int sel = o >> 20;
    const int h = (o >> 16) & 15;
    const int idx = o & 65535;
    const int d = idx >> 10, c = idx & 1023;
    const float* W = (sel == 0 ? Wq : (sel == 1 ? Wk : Wv));
    Wt[o] = f2bf(W[(size_t)h * 65536 + (size_t)c * 64 + d]);
}

// ---- K1: QKV projection via MFMA. xbf[M,C] @ Wt[selh][d][c] -> q/k/v bf16 ---
// block: 4 waves; wave wm owns rows m0+wm*16, all 64 d-cols; K-loop 32 steps.
__global__ __launch_bounds__(256) void qkv_mfma(
    const ushort_t* __restrict__ xbf, const ushort_t* __restrict__ Wt,
    ushort_t* __restrict__ qo, ushort_t* __restrict__ ko, ushort_t* __restrict__ vo)
{
    const int selh = blockIdx.x;             // sel*16 + h
    const int sel = selh >> 4, h = selh & 15;
    const int m0 = blockIdx.y * 64;
    const int tid = threadIdx.x;
    const int wm = tid >> 6, l = tid & 63, lr = l & 15, lg = l >> 4;
    const ushort_t* wrow = Wt + (size_t)selh * (64 * 1024);   // [d][c]
    const ushort_t* xp = xbf + (size_t)(m0 + wm * 16 + lr) * NC + 8 * lg;
    f32x4 acc[4] = {{0,0,0,0},{0,0,0,0},{0,0,0,0},{0,0,0,0}};
    for (int k0 = 0; k0 < NC; k0 += 32) {
        const short8 a = *(const short8*)(xp + k0);
        #pragma unroll
        for (int nt = 0; nt < 4; ++nt) {
            const short8 b = *(const short8*)(wrow + (size_t)(nt * 16 + lr) * NC + k0 + 8 * lg);
            acc[nt] = __builtin_amdgcn_mfma_f32_16x16x32_bf16(a, b, acc[nt], 0, 0, 0);
        }
    }
    ushort_t* outp = (sel == 0 ? qo : (sel == 1 ? ko : vo));
    #pragma unroll
    for (int nt = 0; nt < 4; ++nt) {
        #pragma unroll
        for (int r = 0; r < 4; ++r) {
            const int bt = m0 + wm * 16 + 4 * lg + r;
            const int b = bt >> 11, tt = bt & 2047;
            outp[((size_t)(b * NH + h) * NT + tt) * NHD + nt * 16 + lr] = f2bf(acc[nt][r]);
        }
    }
}

// ---- K2: scores via MFMA, norm fused (pass A: row sums; pass B: write) ------
// S[i][j] = K_i . Q_j / 32 (j<=i); w = exp(S)/rowsum; diag = w[i][i].
__global__ __launch_bounds__(256) void scores_mfma(
    const ushort_t* __restrict__ q, const ushort_t* __restrict__ k,
    float* __restrict__ w, float* __restrict__ diag)
{
    const int ib = blockIdx.x, bh = blockIdx.y;
    const int tid = threadIdx.x;
    const int wm = tid >> 6, l = tid & 63, lr = l & 15, lg = l >> 4;
    const int i0 = ib * 64;
    const ushort_t* kb = k + (size_t)bh * (NT * NHD);
    const ushort_t* qb = q + (size_t)bh * (NT * NHD);
    float* wbase = w + (size_t)bh * SLAB;

    short8 af0, af1;    // A = K rows, m = i_local, 2 k-steps (d 0..31, 32..63)
    {
        const ushort_t* kp = kb + (size_t)(i0 + wm * 16 + lr) * NHD + 8 * lg;
        af0 = *(const short8*)kp;
        af1 = *(const short8*)(kp + 32);
    }
    const int gi_base = i0 + wm * 16 + 4 * lg;     // + r

    float lsum[4] = {0.f, 0.f, 0.f, 0.f};
    for (int jt = 0; jt <= ib; ++jt) {             // PASS A: sums only
        const ushort_t* qt = qb + (size_t)(jt * 64 + lr) * NHD + 8 * lg;
        #pragma unroll
        for (int nt = 0; nt < 4; ++nt) {
            const short8 b0 = *(const short8*)(qt + (size_t)nt * 16 * NHD);
            const short8 b1 = *(const short8*)(qt + (size_t)nt * 16 * NHD + 32);
            f32x4 acc = {0,0,0,0};
            acc = __builtin_amdgcn_mfma_f32_16x16x32_bf16(af0, b0, acc, 0, 0, 0);
            acc = __builtin_amdgcn_mfma_f32_16x16x32_bf16(af1, b1, acc, 0, 0, 0);
            const int gj = jt * 64 + nt * 16 + lr;
            #pragma unroll
            for (int r = 0; r < 4; ++r) {
                float e = __expf(acc[r] * 0.03125f);
                lsum[r] += (gj <= gi_base + r) ? e : 0.f;
            }
        }
    }
    float linv[4];
    #pragma unroll
    for (int r = 0; r < 4; ++r) {
        float v = lsum[r];
        v += __shfl_xor(v, 1);
        v += __shfl_xor(v, 2);
        v += __shfl_xor(v, 4);
        v += __shfl_xor(v, 8);
        linv[r] = 1.0f / v;
    }
    for (int jt = 0; jt <= ib; ++jt) {             // PASS B: write normalized
        const ushort_t* qt = qb + (size_t)(jt * 64 + lr) * NHD + 8 * lg;
        #pragma unroll
        for (int nt = 0; nt < 4; ++nt) {
            const short8 b0 = *(const short8*)(qt + (size_t)nt * 16 * NHD);
            const short8 b1 = *(const short8*)(qt + (size_t)nt * 16 * NHD + 32);
            f32x4 acc = {0,0,0,0};
            acc = __builtin_amdgcn_mfma_f32_16x16x32_bf16(af0, b0, acc, 0, 0, 0);
            acc = __builtin_amdgcn_mfma_f32_16x16x32_bf16(af1, b1, acc, 0, 0, 0);
            const int gj = jt * 64 + nt * 16 + lr;
            #pragma unroll
            for (int r = 0; r < 4; ++r) {
                const int gi = gi_base + r;
                float e = __expf(acc[r] * 0.03125f) * linv[r];
                e = (gj <= gi) ? e : 0.f;
                wbase[(size_t)gi * NT + gj] = e;
                if (gj == gi) diag[(size_t)bh * NT + gi] = e;
            }
        }
    }
    // zero-fill tiles above the diagonal block
    for (int jt = ib + 1; jt < NT / 64; ++jt) {
        #pragma unroll
        for (int it = 0; it < 4; ++it) {
            const int row = i0 + wm * 16 + it * 4 + lg;
            *(float4*)&wbase[(size_t)row * NT + jt * 64 + lr * 4] =
                make_float4(0.f, 0.f, 0.f, 0.f);
        }
    }
}

// ---- K3: out = (diag*v | h-major concat) @ Wp^T + bp (tiled VALU) -----------
__global__ __launch_bounds__(256) void out_proj(
    const ushort_t* __restrict__ v, const float* __restrict__ diag,
    const float* __restrict__ Wp, const float* __restrict__ bpv,
    float* __restrict__ out)
{
    __shared__ float as_[32][68];
    __shared__ float wsp[32][68];
    const int n0 = blockIdx.x * 64;
    const int m0 = blockIdx.y * 64;
    const int t = threadIdx.x;
    const int ty = t >> 4, tx = t & 15;
    float acc[4][4] = {};
    for (int k0 = 0; k0 < NC; k0 += 32) {
        const int h = k0 >> 6, dbase = k0 & 63;
        {
            const int m = t >> 2, kk0 = (t & 3) * 8;
            const int bt = m0 + m, b = bt >> 11, tt = bt & 2047;
            const ushort_t* vp = v + ((size_t)(b * NH + h) * NT + tt) * NHD + dbase + kk0;
            const float dg = diag[(size_t)(b * NH + h) * NT + tt];
            uint4 u = *(const uint4*)vp;
            const ushort_t* us = (const ushort_t*)&u;
            #pragma unroll
            for (int j = 0; j < 8; ++j) as_[kk0 + j][m] = bf2f(us[j]) * dg;
        }
        {
            const int n = t >> 2, kk0 = (t & 3) * 8;
            const float* wp = Wp + (size_t)(n0 + n) * NC + k0 + kk0;
            float4 u0 = *(const float4*)wp;
            float4 u1 = *(const float4*)(wp + 4);
            wsp[kk0 + 0][n] = u0.x; wsp[kk0 + 1][n] = u0.y;
            wsp[kk0 + 2][n] = u0.z; wsp[kk0 + 3][n] = u0.w;
            wsp[kk0 + 4][n] = u1.x; wsp[kk0 + 5][n] = u1.y;
            wsp[kk0 + 6][n] = u1.z; wsp[kk0 + 7][n] = u1.w;
        }
        __syncthreads();
        #pragma unroll 8
        for (int kk = 0; kk < 32; ++kk) {
            const float4 af = *(const float4*)&as_[kk][ty * 4];
            const float4 bf = *(const float4*)&wsp[kk][tx * 4];
            const float a[4] = {af.x, af.y, af.z, af.w};
            const float bb[4] = {bf.x, bf.y, bf.z, bf.w};
            #pragma unroll
            for (int i = 0; i < 4; ++i)
                #pragma unroll
                for (int j = 0; j < 4; ++j)
                    acc[i][j] = fmaf(a[i], bb[j], acc[i][j]);
        }
        __syncthreads();
    }
    float bias[4];
    {
        float4 ub = *(const float4*)&bpv[n0 + tx * 4];
        bias[0] = ub.x; bias[1] = ub.y; bias[2] = ub.z; bias[3] = ub.w;
    }
    #pragma unroll
    for (int i = 0; i < 4; ++i) {
        const int bt = m0 + ty * 4 + i;
        *(float4*)&out[(size_t)bt * NC + n0 + tx * 4] =
            make_float4(acc[i][0] + bias[0], acc[i][1] + bias[1],
                        acc[i][2] + bias[2], acc[i][3] + bias[3]);
    }
}

extern "C" void kernel_launch(void* const* d_in, const int* in_sizes, int n_in,
                              void* d_out, int out_size, void* d_ws, size_t ws_size,
                              hipStream_t stream)
{
    const float* x  = (const float*)d_in[0];
    const float* Wq = (const float*)d_in[1];
    const float* Wk = (const float*)d_in[2];
    const float* Wv = (const float*)d_in[3];
    const float* Wp = (const float*)d_in[4];
    const float* bp = (const float*)d_in[5];

    float* out = (float*)d_out;                      // f32 outputs
    float* w = out + (size_t)NB * NT * NC;           // weights region (f32)

    ushort_t* xbf = (ushort_t*)d_ws;                             // 16.8 MB
    ushort_t* Wt  = xbf + (size_t)NB * NT * NC;                  // 6.3 MB
    ushort_t* qs  = Wt + (size_t)3 * NH * NHD * NC;              // 3 x 16.8 MB
    ushort_t* ks  = qs + (size_t)BH * NT * NHD;
    ushort_t* vs  = ks + (size_t)BH * NT * NHD;
    float* diag   = (float*)(vs + (size_t)BH * NT * NHD);        // 0.5 MB

    cvt_x<<<(NB * NT * NC) / 1024, 256, 0, stream>>>(x, xbf);
    cvt_w<<<(3 * NH * NHD * NC) / 256, 256, 0, stream>>>(Wq, Wk, Wv, Wt);
    qkv_mfma<<<dim3(48, 128), 256, 0, stream>>>(xbf, Wt, qs, ks, vs);
    scores_mfma<<<dim3(NT / 64, BH), 256, 0, stream>>>(qs, ks, w, diag);
    out_proj<<<dim3(16, 128), 256, 0, stream>>>(vs, diag, Wp, bp, out);
}

// Round 13
// 1227.818 us; speedup vs baseline: 7.9034x; 1.0581x over previous
//
#include <hip/hip_runtime.h>

// ROUND 13 — out_proj moved to MFMA: vd = bf16(diag*v) pre-scale, Wp -> bf16,
// out = vd @ Wp^T + bp. qkv/scores unchanged from R12 (passed, absmax 0.0078).

#define NB 4
#define NT 2048
#define NC 1024
#define NH 16
#define NHD 64
#define BH (NB * NH)            // 64
typedef unsigned short ushort_t;
#define SLAB ((size_t)NT * (size_t)NT)

typedef __attribute__((ext_vector_type(8))) short short8;   // 8 bf16 = 4 VGPR
typedef __attribute__((ext_vector_type(4))) float f32x4;

__device__ __forceinline__ ushort_t f2bf(float f) {
    unsigned int x = __float_as_uint(f);
    x += 0x7fffu + ((x >> 16) & 1u);   // RTNE; values finite
    return (ushort_t)(x >> 16);
}
__device__ __forceinline__ float bf2f(ushort_t u) {
    return __uint_as_float(((unsigned int)u) << 16);
}

// ---- P1: x f32 -> xbf bf16 --------------------------------------------------
__global__ __launch_bounds__(256) void cvt_x(
    const float* __restrict__ x, ushort_t* __restrict__ xbf)
{
    const size_t o = ((size_t)blockIdx.x * 256 + threadIdx.x) * 4;
    float4 u = *(const float4*)(x + o);
    ushort4 v;
    v.x = f2bf(u.x); v.y = f2bf(u.y); v.z = f2bf(u.z); v.w = f2bf(u.w);
    *(ushort4*)(xbf + o) = v;
}

// ---- P2: W[sel][h][c][d] f32 -> Wt[sel][h][d][c] bf16 -----------------------
__global__ __launch_bounds__(256) void cvt_w(
    const float* __restrict__ Wq, const float* __restrict__ Wk,
    const float* __restrict__ Wv, ushort_t* __restrict__ Wt)
{
    const int o = blockIdx.x * 256 + threadIdx.x;    // < 3*16*64*1024
    const int sel = o >> 20;
    const int h = (o >> 16) & 15;
    const int idx = o & 65535;
    const int d = idx >> 10, c = idx & 1023;
    const float* W = (sel == 0 ? Wq : (sel == 1 ? Wk : Wv));
    Wt[o] = f2bf(W[(size_t)h * 65536 + (size_t)c * 64 + d]);
}

// ---- P3: Wp f32 [n][c] -> bf16 [n][c] (straight convert) --------------------
__global__ __launch_bounds__(256) void cvt_wp(
    const float* __restrict__ Wp, ushort_t* __restrict__ Wpb)
{
    const size_t o = ((size_t)blockIdx.x * 256 + threadIdx.x) * 4;
    float4 u = *(const float4*)(Wp + o);
    ushort4 v;
    v.x = f2bf(u.x); v.y = f2bf(u.y); v.z = f2bf(u.z); v.w = f2bf(u.w);
    *(ushort4*)(Wpb + o) = v;
}

// ---- K1: QKV projection via MFMA (unchanged, verified R12) ------------------
__global__ __launch_bounds__(256) void qkv_mfma(
    const ushort_t* __restrict__ xbf, const ushort_t* __restrict__ Wt,
    ushort_t* __restrict__ qo, ushort_t* __restrict__ ko, ushort_t* __restrict__ vo)
{
    const int selh = blockIdx.x;             // sel*16 + h
    const int sel = selh >> 4, h = selh & 15;
    const int m0 = blockIdx.y * 64;
    const int tid = threadIdx.x;
    const int wm = tid >> 6, l = tid & 63, lr = l & 15, lg = l >> 4;
    const ushort_t* wrow = Wt + (size_t)selh * (64 * 1024);   // [d][c]
    const ushort_t* xp = xbf + (size_t)(m0 + wm * 16 + lr) * NC + 8 * lg;
    f32x4 acc[4] = {{0,0,0,0},{0,0,0,0},{0,0,0,0},{0,0,0,0}};
    for (int k0 = 0; k0 < NC; k0 += 32) {
        const short8 a = *(const short8*)(xp + k0);
        #pragma unroll
        for (int nt = 0; nt < 4; ++nt) {
            const short8 b = *(const short8*)(wrow + (size_t)(nt * 16 + lr) * NC + k0 + 8 * lg);
            acc[nt] = __builtin_amdgcn_mfma_f32_16x16x32_bf16(a, b, acc[nt], 0, 0, 0);
        }
    }
    ushort_t* outp = (sel == 0 ? qo : (sel == 1 ? ko : vo));
    #pragma unroll
    for (int nt = 0; nt < 4; ++nt) {
        #pragma unroll
        for (int r = 0; r < 4; ++r) {
            const int bt = m0 + wm * 16 + 4 * lg + r;
            const int b = bt >> 11, tt = bt & 2047;
            outp[((size_t)(b * NH + h) * NT + tt) * NHD + nt * 16 + lr] = f2bf(acc[nt][r]);
        }
    }
}

// ---- K2: scores via MFMA, norm fused (unchanged, verified R12) --------------
__global__ __launch_bounds__(256) void scores_mfma(
    const ushort_t* __restrict__ q, const ushort_t* __restrict__ k,
    float* __restrict__ w, float* __restrict__ diag)
{
    const int ib = blockIdx.x, bh = blockIdx.y;
    const int tid = threadIdx.x;
    const int wm = tid >> 6, l = tid & 63, lr = l & 15, lg = l >> 4;
    const int i0 = ib * 64;
    const ushort_t* kb = k + (size_t)bh * (NT * NHD);
    const ushort_t* qb = q + (size_t)bh * (NT * NHD);
    float* wbase = w + (size_t)bh * SLAB;

    short8 af0, af1;    // A = K rows, m = i_local
    {
        const ushort_t* kp = kb + (size_t)(i0 + wm * 16 + lr) * NHD + 8 * lg;
        af0 = *(const short8*)kp;
        af1 = *(const short8*)(kp + 32);
    }
    const int gi_base = i0 + wm * 16 + 4 * lg;     // + r

    float lsum[4] = {0.f, 0.f, 0.f, 0.f};
    for (int jt = 0; jt <= ib; ++jt) {             // PASS A: sums only
        const ushort_t* qt = qb + (size_t)(jt * 64 + lr) * NHD + 8 * lg;
        #pragma unroll
        for (int nt = 0; nt < 4; ++nt) {
            const short8 b0 = *(const short8*)(qt + (size_t)nt * 16 * NHD);
            const short8 b1 = *(const short8*)(qt + (size_t)nt * 16 * NHD + 32);
            f32x4 acc = {0,0,0,0};
            acc = __builtin_amdgcn_mfma_f32_16x16x32_bf16(af0, b0, acc, 0, 0, 0);
            acc = __builtin_amdgcn_mfma_f32_16x16x32_bf16(af1, b1, acc, 0, 0, 0);
            const int gj = jt * 64 + nt * 16 + lr;
            #pragma unroll
            for (int r = 0; r < 4; ++r) {
                float e = __expf(acc[r] * 0.03125f);
                lsum[r] += (gj <= gi_base + r) ? e : 0.f;
            }
        }
    }
    float linv[4];
    #pragma unroll
    for (int r = 0; r < 4; ++r) {
        float v = lsum[r];
        v += __shfl_xor(v, 1);
        v += __shfl_xor(v, 2);
        v += __shfl_xor(v, 4);
        v += __shfl_xor(v, 8);
        linv[r] = 1.0f / v;
    }
    for (int jt = 0; jt <= ib; ++jt) {             // PASS B: write normalized
        const ushort_t* qt = qb + (size_t)(jt * 64 + lr) * NHD + 8 * lg;
        #pragma unroll
        for (int nt = 0; nt < 4; ++nt) {
            const short8 b0 = *(const short8*)(qt + (size_t)nt * 16 * NHD);
            const short8 b1 = *(const short8*)(qt + (size_t)nt * 16 * NHD + 32);
            f32x4 acc = {0,0,0,0};
            acc = __builtin_amdgcn_mfma_f32_16x16x32_bf16(af0, b0, acc, 0, 0, 0);
            acc = __builtin_amdgcn_mfma_f32_16x16x32_bf16(af1, b1, acc, 0, 0, 0);
            const int gj = jt * 64 + nt * 16 + lr;
            #pragma unroll
            for (int r = 0; r < 4; ++r) {
                const int gi = gi_base + r;
                float e = __expf(acc[r] * 0.03125f) * linv[r];
                e = (gj <= gi) ? e : 0.f;
                wbase[(size_t)gi * NT + gj] = e;
                if (gj == gi) diag[(size_t)bh * NT + gi] = e;
            }
        }
    }
    for (int jt = ib + 1; jt < NT / 64; ++jt) {
        #pragma unroll
        for (int it = 0; it < 4; ++it) {
            const int row = i0 + wm * 16 + it * 4 + lg;
            *(float4*)&wbase[(size_t)row * NT + jt * 64 + lr * 4] =
                make_float4(0.f, 0.f, 0.f, 0.f);
        }
    }
}

// ---- P4: vd = bf16(diag * v) ------------------------------------------------
__global__ __launch_bounds__(256) void scale_v(
    const ushort_t* __restrict__ v, const float* __restrict__ diag,
    ushort_t* __restrict__ vd)
{
    const size_t o8 = (size_t)blockIdx.x * 256 + threadIdx.x;  // short8 index
    const size_t o = o8 * 8;
    const size_t bht = o >> 6;                                 // (bh*NT + t)
    const float dg = diag[bht];
    short8 u = *(const short8*)(v + o);
    short8 r;
    #pragma unroll
    for (int j = 0; j < 8; ++j)
        r[j] = (short)f2bf(bf2f((ushort_t)u[j]) * dg);
    *(short8*)(vd + o) = r;
}

// ---- K3: out = vd @ Wp^T + bp via MFMA --------------------------------------
// vd rows: m=(b,t), c = h*64+d (h-major concat, contiguous per head) ✓
// Wpb rows: n, c contiguous ✓.  Same structure as qkv_mfma.
__global__ __launch_bounds__(256) void out_mfma(
    const ushort_t* __restrict__ vd, const ushort_t* __restrict__ Wpb,
    const float* __restrict__ bpv, float* __restrict__ out)
{
    const int n0 = blockIdx.x * 64;
    const int m0 = blockIdx.y * 64;
    const int tid = threadIdx.x;
    const int wm = tid >> 6, l = tid & 63, lr = l & 15, lg = l >> 4;
    // vd is [bh][t][d]; row m=(b,t): c = h*64+d -> addr ((b*16+h)*2048+t)*64+d
    const int bt = m0 + wm * 16 + lr;
    const int b = bt >> 11, tt = bt & 2047;
    const ushort_t* vrow_base = vd + ((size_t)b * NH * NT + tt) * NHD;  // + h*NT*64 + d
    f32x4 acc[4] = {{0,0,0,0},{0,0,0,0},{0,0,0,0},{0,0,0,0}};
    for (int k0 = 0; k0 < NC; k0 += 32) {
        const int h = k0 >> 6, d0 = k0 & 63;
        const short8 a = *(const short8*)(vrow_base + (size_t)h * (NT * NHD) + d0 + 8 * lg);
        #pragma unroll
        for (int nt = 0; nt < 4; ++nt) {
            const short8 bfr = *(const short8*)(Wpb + (size_t)(n0 + nt * 16 + lr) * NC + k0 + 8 * lg);
            acc[nt] = __builtin_amdgcn_mfma_f32_16x16x32_bf16(a, bfr, acc[nt], 0, 0, 0);
        }
    }
    #pragma unroll
    for (int nt = 0; nt < 4; ++nt) {
        const float bias = bpv[n0 + nt * 16 + lr];
        #pragma unroll
        for (int r = 0; r < 4; ++r) {
            const int m = m0 + wm * 16 + 4 * lg + r;
            out[(size_t)m * NC + n0 + nt * 16 + lr] = acc[nt][r] + bias;
        }
    }
}

extern "C" void kernel_launch(void* const* d_in, const int* in_sizes, int n_in,
                              void* d_out, int out_size, void* d_ws, size_t ws_size,
                              hipStream_t stream)
{
    const float* x  = (const float*)d_in[0];
    const float* Wq = (const float*)d_in[1];
    const float* Wk = (const float*)d_in[2];
    const float* Wv = (const float*)d_in[3];
    const float* Wp = (const float*)d_in[4];
    const float* bp = (const float*)d_in[5];

    float* out = (float*)d_out;                      // f32 outputs
    float* w = out + (size_t)NB * NT * NC;           // weights region (f32)

    ushort_t* xbf = (ushort_t*)d_ws;                             // 16.8 MB
    ushort_t* Wt  = xbf + (size_t)NB * NT * NC;                  // 6.3 MB
    ushort_t* qs  = Wt + (size_t)3 * NH * NHD * NC;              // 3 x 16.8 MB
    ushort_t* ks  = qs + (size_t)BH * NT * NHD;
    ushort_t* vs  = ks + (size_t)BH * NT * NHD;
    float* diag   = (float*)(vs + (size_t)BH * NT * NHD);        // 0.5 MB
    ushort_t* Wpb = (ushort_t*)(diag + (size_t)BH * NT);         // 2 MB
    ushort_t* vd  = Wpb + (size_t)NC * NC;                       // 16.8 MB

    cvt_x<<<(NB * NT * NC) / 1024, 256, 0, stream>>>(x, xbf);
    cvt_w<<<(3 * NH * NHD * NC) / 256, 256, 0, stream>>>(Wq, Wk, Wv, Wt);
    cvt_wp<<<(NC * NC) / 1024, 256, 0, stream>>>(Wp, Wpb);
    qkv_mfma<<<dim3(48, 128), 256, 0, stream>>>(xbf, Wt, qs, ks, vs);
    scores_mfma<<<dim3(NT / 64, BH), 256, 0, stream>>>(qs, ks, w, diag);
    scale_v<<<(BH * NT * NHD) / (256 * 8), 256, 0, stream>>>(vs, diag, vd);
    out_mfma<<<dim3(16, 128), 256, 0, stream>>>(vd, Wpb, bp, out);
}

// Round 14
// 863.741 us; speedup vs baseline: 11.2348x; 1.4215x over previous
//
#include <hip/hip_runtime.h>

// ROUND 14 — qkv rebuilt as m97-style LDS-staged GEMM (128x128 tile, BK=64,
// global_load_lds 16B, XOR-swizzled LDS). scores/out/cvt unchanged from R13.

#define NB 4
#define NT 2048
#define NC 1024
#define NH 16
#define NHD 64
#define BH (NB * NH)            // 64
typedef unsigned short ushort_t;
#define SLAB ((size_t)NT * (size_t)NT)

typedef __attribute__((ext_vector_type(8))) short short8;   // 8 bf16 = 4 VGPR
typedef __attribute__((ext_vector_type(4))) float f32x4;

__device__ __forceinline__ ushort_t f2bf(float f) {
    unsigned int x = __float_as_uint(f);
    x += 0x7fffu + ((x >> 16) & 1u);   // RTNE; values finite
    return (ushort_t)(x >> 16);
}
__device__ __forceinline__ float bf2f(ushort_t u) {
    return __uint_as_float(((unsigned int)u) << 16);
}

#define GLD_LDS16(g, l) \
    __builtin_amdgcn_global_load_lds( \
        (const __attribute__((address_space(1))) unsigned int*)(g), \
        (__attribute__((address_space(3))) unsigned int*)(l), 16, 0, 0)

// ---- P1: x f32 -> xbf bf16 --------------------------------------------------
__global__ __launch_bounds__(256) void cvt_x(
    const float* __restrict__ x, ushort_t* __restrict__ xbf)
{
    const size_t o = ((size_t)blockIdx.x * 256 + threadIdx.x) * 4;
    float4 u = *(const float4*)(x + o);
    ushort4 v;
    v.x = f2bf(u.x); v.y = f2bf(u.y); v.z = f2bf(u.z); v.w = f2bf(u.w);
    *(ushort4*)(xbf + o) = v;
}

// ---- P2: W[sel][h][c][d] f32 -> Wt[n][c] bf16 (n = sel*1024+h*64+d) ---------
__global__ __launch_bounds__(256) void cvt_w(
    const float* __restrict__ Wq, const float* __restrict__ Wk,
    const float* __restrict__ Wv, ushort_t* __restrict__ Wt)
{
    const int o = blockIdx.x * 256 + threadIdx.x;    // < 3*16*64*1024
    const int sel = o >> 20;
    const int h = (o >> 16) & 15;
    const int idx = o & 65535;
    const int d = idx >> 10, c = idx & 1023;
    const float* W = (sel == 0 ? Wq : (sel == 1 ? Wk : Wv));
    Wt[o] = f2bf(W[(size_t)h * 65536 + (size_t)c * 64 + d]);
}

// ---- P3: Wp f32 [n][c] -> bf16 ----------------------------------------------
__global__ __launch_bounds__(256) void cvt_wp(
    const float* __restrict__ Wp, ushort_t* __restrict__ Wpb)
{
    const size_t o = ((size_t)blockIdx.x * 256 + threadIdx.x) * 4;
    float4 u = *(const float4*)(Wp + o);
    ushort4 v;
    v.x = f2bf(u.x); v.y = f2bf(u.y); v.z = f2bf(u.z); v.w = f2bf(u.w);
    *(ushort4*)(Wpb + o) = v;
}

// ---- K1: qkv GEMM, m97-style. C[8192, 3072] = xbf[8192,1024] @ Wt[3072,1024]^T
// 128x128 tile, BK=64, 4 waves in 2x2 quadrants of 64x64, 4x4 frags 16x16x32.
// LDS [128][64] bf16 per operand, XOR-swizzle byte^=((row&7)<<4) (src pre-swz).
__global__ __launch_bounds__(256) void qkv_gemm2(
    const ushort_t* __restrict__ xbf, const ushort_t* __restrict__ Wt,
    ushort_t* __restrict__ qo, ushort_t* __restrict__ ko, ushort_t* __restrict__ vo)
{
    __shared__ ushort_t smA[128 * 64];   // 16 KB
    __shared__ ushort_t smB[128 * 64];   // 16 KB
    const int n0 = blockIdx.x * 128;
    const int m0 = blockIdx.y * 128;
    const int tid = threadIdx.x;
    const int wid = tid >> 6, l = tid & 63, lr = l & 15, lg = l >> 4;
    const int wr = wid >> 1, wc = wid & 1;

    // staging lane map (per wave-instr j): linear LDS o = wid*4KB + j*1KB + l*16B
    const int srow = wid * 32 + (l >> 3);            // + j*8
    const int scol0 = ((l & 7) ^ (srow & 7)) * 8;    // pre-swizzled k-elem offset
    // NOTE: srow&7 depends on j*8 only via bit3+ -> (srow + j*8)&7 == srow&7 ✓

    f32x4 acc[4][4];
    #pragma unroll
    for (int i = 0; i < 4; ++i)
        #pragma unroll
        for (int j = 0; j < 4; ++j) acc[i][j] = (f32x4){0.f, 0.f, 0.f, 0.f};

    for (int k0 = 0; k0 < NC; k0 += 64) {
        #pragma unroll
        for (int j = 0; j < 4; ++j) {
            const int row = srow + j * 8;
            GLD_LDS16(xbf + (size_t)(m0 + row) * NC + k0 + scol0,
                      &smA[wid * 2048 + j * 512]);
            GLD_LDS16(Wt + (size_t)(n0 + row) * NC + k0 + scol0,
                      &smB[wid * 2048 + j * 512]);
        }
        __syncthreads();
        short8 a[4][2], b[4][2];
        #pragma unroll
        for (int mi = 0; mi < 4; ++mi) {
            const int rowA = 64 * wr + 16 * mi + lr;
            const int sw = (rowA & 7) * 8;
            a[mi][0] = *(const short8*)&smA[rowA * 64 + ((8 * lg) ^ sw)];
            a[mi][1] = *(const short8*)&smA[rowA * 64 + ((32 + 8 * lg) ^ sw)];
        }
        #pragma unroll
        for (int ni = 0; ni < 4; ++ni) {
            const int rowB = 64 * wc + 16 * ni + lr;
            const int sw = (rowB & 7) * 8;
            b[ni][0] = *(const short8*)&smB[rowB * 64 + ((8 * lg) ^ sw)];
            b[ni][1] = *(const short8*)&smB[rowB * 64 + ((32 + 8 * lg) ^ sw)];
        }
        #pragma unroll
        for (int mi = 0; mi < 4; ++mi)
            #pragma unroll
            for (int ni = 0; ni < 4; ++ni) {
                acc[mi][ni] = __builtin_amdgcn_mfma_f32_16x16x32_bf16(
                    a[mi][0], b[ni][0], acc[mi][ni], 0, 0, 0);
                acc[mi][ni] = __builtin_amdgcn_mfma_f32_16x16x32_bf16(
                    a[mi][1], b[ni][1], acc[mi][ni], 0, 0, 0);
            }
        __syncthreads();
    }
    // epilogue: selh constant per wave-column
    const int selh = blockIdx.x * 2 + wc;
    const int sel = selh >> 4, h = selh & 15;
    ushort_t* outp = (sel == 0 ? qo : (sel == 1 ? ko : vo));
    #pragma unroll
    for (int mi = 0; mi < 4; ++mi) {
        #pragma unroll
        for (int r = 0; r < 4; ++r) {
            const int m = m0 + 64 * wr + 16 * mi + 4 * lg + r;
            const int bb = m >> 11, tt = m & 2047;
            ushort_t* orow = outp + ((size_t)(bb * NH + h) * NT + tt) * NHD;
            #pragma unroll
            for (int ni = 0; ni < 4; ++ni)
                orow[16 * ni + lr] = f2bf(acc[mi][ni][r]);
        }
    }
}

// ---- K2: scores via MFMA, norm fused (unchanged, verified R12/R13) ----------
__global__ __launch_bounds__(256) void scores_mfma(
    const ushort_t* __restrict__ q, const ushort_t* __restrict__ k,
    float* __restrict__ w, float* __restrict__ diag)
{
    const int ib = blockIdx.x, bh = blockIdx.y;
    const int tid = threadIdx.x;
    const int wm = tid >> 6, l = tid & 63, lr = l & 15, lg = l >> 4;
    const int i0 = ib * 64;
    const ushort_t* kb = k + (size_t)bh * (NT * NHD);
    const ushort_t* qb = q + (size_t)bh * (NT * NHD);
    float* wbase = w + (size_t)bh * SLAB;

    short8 af0, af1;    // A = K rows, m = i_local
    {
        const ushort_t* kp = kb + (size_t)(i0 + wm * 16 + lr) * NHD + 8 * lg;
        af0 = *(const short8*)kp;
        af1 = *(const short8*)(kp + 32);
    }
    const int gi_base = i0 + wm * 16 + 4 * lg;     // + r

    float lsum[4] = {0.f, 0.f, 0.f, 0.f};
    for (int jt = 0; jt <= ib; ++jt) {             // PASS A: sums only
        const ushort_t* qt = qb + (size_t)(jt * 64 + lr) * NHD + 8 * lg;
        #pragma unroll
        for (int nt = 0; nt < 4; ++nt) {
            const short8 b0 = *(const short8*)(qt + (size_t)nt * 16 * NHD);
            const short8 b1 = *(const short8*)(qt + (size_t)nt * 16 * NHD + 32);
            f32x4 acc = {0,0,0,0};
            acc = __builtin_amdgcn_mfma_f32_16x16x32_bf16(af0, b0, acc, 0, 0, 0);
            acc = __builtin_amdgcn_mfma_f32_16x16x32_bf16(af1, b1, acc, 0, 0, 0);
            const int gj = jt * 64 + nt * 16 + lr;
            #pragma unroll
            for (int r = 0; r < 4; ++r) {
                float e = __expf(acc[r] * 0.03125f);
                lsum[r] += (gj <= gi_base + r) ? e : 0.f;
            }
        }
    }
    float linv[4];
    #pragma unroll
    for (int r = 0; r < 4; ++r) {
        float v = lsum[r];
        v += __shfl_xor(v, 1);
        v += __shfl_xor(v, 2);
        v += __shfl_xor(v, 4);
        v += __shfl_xor(v, 8);
        linv[r] = 1.0f / v;
    }
    for (int jt = 0; jt <= ib; ++jt) {             // PASS B: write normalized
        const ushort_t* qt = qb + (size_t)(jt * 64 + lr) * NHD + 8 * lg;
        #pragma unroll
        for (int nt = 0; nt < 4; ++nt) {
            const short8 b0 = *(const short8*)(qt + (size_t)nt * 16 * NHD);
            const short8 b1 = *(const short8*)(qt + (size_t)nt * 16 * NHD + 32);
            f32x4 acc = {0,0,0,0};
            acc = __builtin_amdgcn_mfma_f32_16x16x32_bf16(af0, b0, acc, 0, 0, 0);
            acc = __builtin_amdgcn_mfma_f32_16x16x32_bf16(af1, b1, acc, 0, 0, 0);
            const int gj = jt * 64 + nt * 16 + lr;
            #pragma unroll
            for (int r = 0; r < 4; ++r) {
                const int gi = gi_base + r;
                float e = __expf(acc[r] * 0.03125f) * linv[r];
                e = (gj <= gi) ? e : 0.f;
                wbase[(size_t)gi * NT + gj] = e;
                if (gj == gi) diag[(size_t)bh * NT + gi] = e;
            }
        }
    }
    for (int jt = ib + 1; jt < NT / 64; ++jt) {
        #pragma unroll
        for (int it = 0; it < 4; ++it) {
            const int row = i0 + wm * 16 + it * 4 + lg;
            *(float4*)&wbase[(size_t)row * NT + jt * 64 + lr * 4] =
                make_float4(0.f, 0.f, 0.f, 0.f);
        }
    }
}

// ---- P4: vd = bf16(diag * v) ------------------------------------------------
__global__ __launch_bounds__(256) void scale_v(
    const ushort_t* __restrict__ v, const float* __restrict__ diag,
    ushort_t* __restrict__ vd)
{
    const size_t o8 = (size_t)blockIdx.x * 256 + threadIdx.x;  // short8 index
    const size_t o = o8 * 8;
    const size_t bht = o >> 6;                                 // (bh*NT + t)
    const float dg = diag[bht];
    short8 u = *(const short8*)(v + o);
    short8 r;
    #pragma unroll
    for (int j = 0; j < 8; ++j)
        r[j] = (short)f2bf(bf2f((ushort_t)u[j]) * dg);
    *(short8*)(vd + o) = r;
}

// ---- K3: out = vd @ Wp^T + bp via MFMA (unchanged, verified R13) ------------
__global__ __launch_bounds__(256) void out_mfma(
    const ushort_t* __restrict__ vd, const ushort_t* __restrict__ Wpb,
    const float* __restrict__ bpv, float* __restrict__ out)
{
    const int n0 = blockIdx.x * 64;
    const int m0 = blockIdx.y * 64;
    const int tid = threadIdx.x;
    const int wm = tid >> 6, l = tid & 63, lr = l & 15, lg = l >> 4;
    const int bt = m0 + wm * 16 + lr;
    const int b = bt >> 11, tt = bt & 2047;
    const ushort_t* vrow_base = vd + ((size_t)b * NH * NT + tt) * NHD;
    f32x4 acc[4] = {{0,0,0,0},{0,0,0,0},{0,0,0,0},{0,0,0,0}};
    for (int k0 = 0; k0 < NC; k0 += 32) {
        const int h = k0 >> 6, d0 = k0 & 63;
        const short8 a = *(const short8*)(vrow_base + (size_t)h * (NT * NHD) + d0 + 8 * lg);
        #pragma unroll
        for (int nt = 0; nt < 4; ++nt) {
            const short8 bfr = *(const short8*)(Wpb + (size_t)(n0 + nt * 16 + lr) * NC + k0 + 8 * lg);
            acc[nt] = __builtin_amdgcn_mfma_f32_16x16x32_bf16(a, bfr, acc[nt], 0, 0, 0);
        }
    }
    #pragma unroll
    for (int nt = 0; nt < 4; ++nt) {
        const float bias = bpv[n0 + nt * 16 + lr];
        #pragma unroll
        for (int r = 0; r < 4; ++r) {
            const int m = m0 + wm * 16 + 4 * lg + r;
            out[(size_t)m * NC + n0 + nt * 16 + lr] = acc[nt][r] + bias;
        }
    }
}

extern "C" void kernel_launch(void* const* d_in, const int* in_sizes, int n_in,
                              void* d_out, int out_size, void* d_ws, size_t ws_size,
                              hipStream_t stream)
{
    const float* x  = (const float*)d_in[0];
    const float* Wq = (const float*)d_in[1];
    const float* Wk = (const float*)d_in[2];
    const float* Wv = (const float*)d_in[3];
    const float* Wp = (const float*)d_in[4];
    const float* bp = (const float*)d_in[5];

    float* out = (float*)d_out;                      // f32 outputs
    float* w = out + (size_t)NB * NT * NC;           // weights region (f32)

    ushort_t* xbf = (ushort_t*)d_ws;                             // 16.8 MB
    ushort_t* Wt  = xbf + (size_t)NB * NT * NC;                  // 6.3 MB
    ushort_t* qs  = Wt + (size_t)3 * NH * NHD * NC;              // 3 x 16.8 MB
    ushort_t* ks  = qs + (size_t)BH * NT * NHD;
    ushort_t* vs  = ks + (size_t)BH * NT * NHD;
    float* diag   = (float*)(vs + (size_t)BH * NT * NHD);        // 0.5 MB
    ushort_t* Wpb = (ushort_t*)(diag + (size_t)BH * NT);         // 2 MB
    ushort_t* vd  = Wpb + (size_t)NC * NC;                       // 16.8 MB

    cvt_x<<<(NB * NT * NC) / 1024, 256, 0, stream>>>(x, xbf);
    cvt_w<<<(3 * NH * NHD * NC) / 256, 256, 0, stream>>>(Wq, Wk, Wv, Wt);
    cvt_wp<<<(NC * NC) / 1024, 256, 0, stream>>>(Wp, Wpb);
    qkv_gemm2<<<dim3(24, 64), 256, 0, stream>>>(xbf, Wt, qs, ks, vs);
    scores_mfma<<<dim3(NT / 64, BH), 256, 0, stream>>>(qs, ks, w, diag);
    scale_v<<<(BH * NT * NHD) / (256 * 8), 256, 0, stream>>>(vs, diag, vd);
    out_mfma<<<dim3(16, 128), 256, 0, stream>>>(vd, Wpb, bp, out);
}

// Round 15
// 451.285 us; speedup vs baseline: 21.5029x; 1.9140x over previous
//
#include <hip/hip_runtime.h>

// ROUND 15 — scores: Q-tiles LDS-staged (shared across waves, XOR-swizzled);
// out: rebuilt as 128x128 LDS-staged MFMA GEMM. qkv/cvt/scale_v unchanged (R14).

#define NB 4
#define NT 2048
#define NC 1024
#define NH 16
#define NHD 64
#define BH (NB * NH)            // 64
typedef unsigned short ushort_t;
#define SLAB ((size_t)NT * (size_t)NT)

typedef __attribute__((ext_vector_type(8))) short short8;   // 8 bf16 = 4 VGPR
typedef __attribute__((ext_vector_type(4))) float f32x4;

__device__ __forceinline__ ushort_t f2bf(float f) {
    unsigned int x = __float_as_uint(f);
    x += 0x7fffu + ((x >> 16) & 1u);   // RTNE; values finite
    return (ushort_t)(x >> 16);
}
__device__ __forceinline__ float bf2f(ushort_t u) {
    return __uint_as_float(((unsigned int)u) << 16);
}

#define GLD_LDS16(g, l) \
    __builtin_amdgcn_global_load_lds( \
        (const __attribute__((address_space(1))) unsigned int*)(g), \
        (__attribute__((address_space(3))) unsigned int*)(l), 16, 0, 0)

// ---- P1: x f32 -> xbf bf16 --------------------------------------------------
__global__ __launch_bounds__(256) void cvt_x(
    const float* __restrict__ x, ushort_t* __restrict__ xbf)
{
    const size_t o = ((size_t)blockIdx.x * 256 + threadIdx.x) * 4;
    float4 u = *(const float4*)(x + o);
    ushort4 v;
    v.x = f2bf(u.x); v.y = f2bf(u.y); v.z = f2bf(u.z); v.w = f2bf(u.w);
    *(ushort4*)(xbf + o) = v;
}

// ---- P2: W[sel][h][c][d] f32 -> Wt[n][c] bf16 (n = sel*1024+h*64+d) ---------
__global__ __launch_bounds__(256) void cvt_w(
    const float* __restrict__ Wq, const float* __restrict__ Wk,
    const float* __restrict__ Wv, ushort_t* __restrict__ Wt)
{
    const int o = blockIdx.x * 256 + threadIdx.x;    // < 3*16*64*1024
    const int sel = o >> 20;
    const int h = (o >> 16) & 15;
    const int idx = o & 65535;
    const int d = idx >> 10, c = idx & 1023;
    const float* W = (sel == 0 ? Wq : (sel == 1 ? Wk : Wv));
    Wt[o] = f2bf(W[(size_t)h * 65536 + (size_t)c * 64 + d]);
}

// ---- P3: Wp f32 [n][c] -> bf16 ----------------------------------------------
__global__ __launch_bounds__(256) void cvt_wp(
    const float* __restrict__ Wp, ushort_t* __restrict__ Wpb)
{
    const size_t o = ((size_t)blockIdx.x * 256 + threadIdx.x) * 4;
    float4 u = *(const float4*)(Wp + o);
    ushort4 v;
    v.x = f2bf(u.x); v.y = f2bf(u.y); v.z = f2bf(u.z); v.w = f2bf(u.w);
    *(ushort4*)(Wpb + o) = v;
}

// ---- K1: qkv GEMM (verified R14) --------------------------------------------
__global__ __launch_bounds__(256) void qkv_gemm2(
    const ushort_t* __restrict__ xbf, const ushort_t* __restrict__ Wt,
    ushort_t* __restrict__ qo, ushort_t* __restrict__ ko, ushort_t* __restrict__ vo)
{
    __shared__ ushort_t smA[128 * 64];   // 16 KB
    __shared__ ushort_t smB[128 * 64];   // 16 KB
    const int n0 = blockIdx.x * 128;
    const int m0 = blockIdx.y * 128;
    const int tid = threadIdx.x;
    const int wid = tid >> 6, l = tid & 63, lr = l & 15, lg = l >> 4;
    const int wr = wid >> 1, wc = wid & 1;

    const int srow = wid * 32 + (l >> 3);            // + j*8
    const int scol0 = ((l & 7) ^ (srow & 7)) * 8;    // pre-swizzled elem offset

    f32x4 acc[4][4];
    #pragma unroll
    for (int i = 0; i < 4; ++i)
        #pragma unroll
        for (int j = 0; j < 4; ++j) acc[i][j] = (f32x4){0.f, 0.f, 0.f, 0.f};

    for (int k0 = 0; k0 < NC; k0 += 64) {
        #pragma unroll
        for (int j = 0; j < 4; ++j) {
            const int row = srow + j * 8;
            GLD_LDS16(xbf + (size_t)(m0 + row) * NC + k0 + scol0,
                      &smA[wid * 2048 + j * 512]);
            GLD_LDS16(Wt + (size_t)(n0 + row) * NC + k0 + scol0,
                      &smB[wid * 2048 + j * 512]);
        }
        __syncthreads();
        short8 a[4][2], b[4][2];
        #pragma unroll
        for (int mi = 0; mi < 4; ++mi) {
            const int rowA = 64 * wr + 16 * mi + lr;
            const int sw = (rowA & 7) * 8;
            a[mi][0] = *(const short8*)&smA[rowA * 64 + ((8 * lg) ^ sw)];
            a[mi][1] = *(const short8*)&smA[rowA * 64 + ((32 + 8 * lg) ^ sw)];
        }
        #pragma unroll
        for (int ni = 0; ni < 4; ++ni) {
            const int rowB = 64 * wc + 16 * ni + lr;
            const int sw = (rowB & 7) * 8;
            b[ni][0] = *(const short8*)&smB[rowB * 64 + ((8 * lg) ^ sw)];
            b[ni][1] = *(const short8*)&smB[rowB * 64 + ((32 + 8 * lg) ^ sw)];
        }
        #pragma unroll
        for (int mi = 0; mi < 4; ++mi)
            #pragma unroll
            for (int ni = 0; ni < 4; ++ni) {
                acc[mi][ni] = __builtin_amdgcn_mfma_f32_16x16x32_bf16(
                    a[mi][0], b[ni][0], acc[mi][ni], 0, 0, 0);
                acc[mi][ni] = __builtin_amdgcn_mfma_f32_16x16x32_bf16(
                    a[mi][1], b[ni][1], acc[mi][ni], 0, 0, 0);
            }
        __syncthreads();
    }
    const int selh = blockIdx.x * 2 + wc;
    const int sel = selh >> 4, h = selh & 15;
    ushort_t* outp = (sel == 0 ? qo : (sel == 1 ? ko : vo));
    #pragma unroll
    for (int mi = 0; mi < 4; ++mi) {
        #pragma unroll
        for (int r = 0; r < 4; ++r) {
            const int m = m0 + 64 * wr + 16 * mi + 4 * lg + r;
            const int bb = m >> 11, tt = m & 2047;
            ushort_t* orow = outp + ((size_t)(bb * NH + h) * NT + tt) * NHD;
            #pragma unroll
            for (int ni = 0; ni < 4; ++ni)
                orow[16 * ni + lr] = f2bf(acc[mi][ni][r]);
        }
    }
}

// ---- K2: scores via MFMA, Q-tile LDS-staged, norm fused ---------------------
__global__ __launch_bounds__(256) void scores_mfma(
    const ushort_t* __restrict__ q, const ushort_t* __restrict__ k,
    float* __restrict__ w, float* __restrict__ diag)
{
    __shared__ ushort_t smQ[64 * 64];    // 8 KB
    const int ib = blockIdx.x, bh = blockIdx.y;
    const int tid = threadIdx.x;
    const int wid = tid >> 6, l = tid & 63, lr = l & 15, lg = l >> 4;
    const int i0 = ib * 64;
    const ushort_t* kb = k + (size_t)bh * (NT * NHD);
    const ushort_t* qb = q + (size_t)bh * (NT * NHD);
    float* wbase = w + (size_t)bh * SLAB;

    short8 af0, af1;    // A = K rows, m = i_local
    {
        const ushort_t* kp = kb + (size_t)(i0 + wid * 16 + lr) * NHD + 8 * lg;
        af0 = *(const short8*)kp;
        af1 = *(const short8*)(kp + 32);
    }
    const int gi_base = i0 + wid * 16 + 4 * lg;     // + r

    // staging map: wave wid stages rows wid*16 + j*8 + (l>>3), j=0,1
    const int srlo = l >> 3;                        // 0..7
    const int scol = ((l & 7) ^ srlo) * 8;          // pre-swizzled elem offset

    float lsum[4] = {0.f, 0.f, 0.f, 0.f};
    for (int jt = 0; jt <= ib; ++jt) {             // PASS A: sums only
        #pragma unroll
        for (int j = 0; j < 2; ++j) {
            const int row = wid * 16 + j * 8 + srlo;
            GLD_LDS16(qb + (size_t)(jt * 64 + row) * NHD + scol,
                      &smQ[(wid * 16 + j * 8) * 64]);
        }
        __syncthreads();
        #pragma unroll
        for (int nt = 0; nt < 4; ++nt) {
            const int rowB = nt * 16 + lr;
            const int sw = (rowB & 7) * 8;
            const short8 b0 = *(const short8*)&smQ[rowB * 64 + ((8 * lg) ^ sw)];
            const short8 b1 = *(const short8*)&smQ[rowB * 64 + ((32 + 8 * lg) ^ sw)];
            f32x4 acc = {0,0,0,0};
            acc = __builtin_amdgcn_mfma_f32_16x16x32_bf16(af0, b0, acc, 0, 0, 0);
            acc = __builtin_amdgcn_mfma_f32_16x16x32_bf16(af1, b1, acc, 0, 0, 0);
            const int gj = jt * 64 + nt * 16 + lr;
            #pragma unroll
            for (int r = 0; r < 4; ++r) {
                float e = __expf(acc[r] * 0.03125f);
                lsum[r] += (gj <= gi_base + r) ? e : 0.f;
            }
        }
        __syncthreads();
    }
    float linv[4];
    #pragma unroll
    for (int r = 0; r < 4; ++r) {
        float v = lsum[r];
        v += __shfl_xor(v, 1);
        v += __shfl_xor(v, 2);
        v += __shfl_xor(v, 4);
        v += __shfl_xor(v, 8);
        linv[r] = 1.0f / v;
    }
    for (int jt = 0; jt <= ib; ++jt) {             // PASS B: write normalized
        #pragma unroll
        for (int j = 0; j < 2; ++j) {
            const int row = wid * 16 + j * 8 + srlo;
            GLD_LDS16(qb + (size_t)(jt * 64 + row) * NHD + scol,
                      &smQ[(wid * 16 + j * 8) * 64]);
        }
        __syncthreads();
        #pragma unroll
        for (int nt = 0; nt < 4; ++nt) {
            const int rowB = nt * 16 + lr;
            const int sw = (rowB & 7) * 8;
            const short8 b0 = *(const short8*)&smQ[rowB * 64 + ((8 * lg) ^ sw)];
            const short8 b1 = *(const short8*)&smQ[rowB * 64 + ((32 + 8 * lg) ^ sw)];
            f32x4 acc = {0,0,0,0};
            acc = __builtin_amdgcn_mfma_f32_16x16x32_bf16(af0, b0, acc, 0, 0, 0);
            acc = __builtin_amdgcn_mfma_f32_16x16x32_bf16(af1, b1, acc, 0, 0, 0);
            const int gj = jt * 64 + nt * 16 + lr;
            #pragma unroll
            for (int r = 0; r < 4; ++r) {
                const int gi = gi_base + r;
                float e = __expf(acc[r] * 0.03125f) * linv[r];
                e = (gj <= gi) ? e : 0.f;
                wbase[(size_t)gi * NT + gj] = e;
                if (gj == gi) diag[(size_t)bh * NT + gi] = e;
            }
        }
        __syncthreads();
    }
    for (int jt = ib + 1; jt < NT / 64; ++jt) {
        #pragma unroll
        for (int it = 0; it < 4; ++it) {
            const int row = i0 + wid * 16 + it * 4 + lg;
            *(float4*)&wbase[(size_t)row * NT + jt * 64 + lr * 4] =
                make_float4(0.f, 0.f, 0.f, 0.f);
        }
    }
}

// ---- P4: vd = bf16(diag * v) ------------------------------------------------
__global__ __launch_bounds__(256) void scale_v(
    const ushort_t* __restrict__ v, const float* __restrict__ diag,
    ushort_t* __restrict__ vd)
{
    const size_t o8 = (size_t)blockIdx.x * 256 + threadIdx.x;  // short8 index
    const size_t o = o8 * 8;
    const size_t bht = o >> 6;                                 // (bh*NT + t)
    const float dg = diag[bht];
    short8 u = *(const short8*)(v + o);
    short8 r;
    #pragma unroll
    for (int j = 0; j < 8; ++j)
        r[j] = (short)f2bf(bf2f((ushort_t)u[j]) * dg);
    *(short8*)(vd + o) = r;
}

// ---- K3: out = vd @ Wp^T + bp, 128x128 LDS-staged MFMA GEMM -----------------
// A row m=(b,t): col c=h*64+d at vd[((b*16+h)*2048+t)*64+d]; 16B chunks stay
// within one head at BK=64, so per-lane staging sources are contiguous.
__global__ __launch_bounds__(256) void out_gemm(
    const ushort_t* __restrict__ vd, const ushort_t* __restrict__ Wpb,
    const float* __restrict__ bpv, float* __restrict__ out)
{
    __shared__ ushort_t smA[128 * 64];   // 16 KB
    __shared__ ushort_t smB[128 * 64];   // 16 KB
    const int n0 = blockIdx.x * 128;
    const int m0 = blockIdx.y * 128;
    const int tid = threadIdx.x;
    const int wid = tid >> 6, l = tid & 63, lr = l & 15, lg = l >> 4;
    const int wr = wid >> 1, wc = wid & 1;

    const int srow = wid * 32 + (l >> 3);            // + j*8
    const int scol0 = ((l & 7) ^ (srow & 7)) * 8;    // pre-swizzled elem offset

    f32x4 acc[4][4];
    #pragma unroll
    for (int i = 0; i < 4; ++i)
        #pragma unroll
        for (int j = 0; j < 4; ++j) acc[i][j] = (f32x4){0.f, 0.f, 0.f, 0.f};

    for (int k0 = 0; k0 < NC; k0 += 64) {
        const int h = k0 >> 6;
        #pragma unroll
        for (int j = 0; j < 4; ++j) {
            const int row = srow + j * 8;
            const int m = m0 + row, bb = m >> 11, tt = m & 2047;
            GLD_LDS16(vd + ((size_t)(bb * NH + h) * NT + tt) * NHD + scol0,
                      &smA[wid * 2048 + j * 512]);
            GLD_LDS16(Wpb + (size_t)(n0 + row) * NC + k0 + scol0,
                      &smB[wid * 2048 + j * 512]);
        }
        __syncthreads();
        short8 a[4][2], b[4][2];
        #pragma unroll
        for (int mi = 0; mi < 4; ++mi) {
            const int rowA = 64 * wr + 16 * mi + lr;
            const int sw = (rowA & 7) * 8;
            a[mi][0] = *(const short8*)&smA[rowA * 64 + ((8 * lg) ^ sw)];
            a[mi][1] = *(const short8*)&smA[rowA * 64 + ((32 + 8 * lg) ^ sw)];
        }
        #pragma unroll
        for (int ni = 0; ni < 4; ++ni) {
            const int rowB = 64 * wc + 16 * ni + lr;
            const int sw = (rowB & 7) * 8;
            b[ni][0] = *(const short8*)&smB[rowB * 64 + ((8 * lg) ^ sw)];
            b[ni][1] = *(const short8*)&smB[rowB * 64 + ((32 + 8 * lg) ^ sw)];
        }
        #pragma unroll
        for (int mi = 0; mi < 4; ++mi)
            #pragma unroll
            for (int ni = 0; ni < 4; ++ni) {
                acc[mi][ni] = __builtin_amdgcn_mfma_f32_16x16x32_bf16(
                    a[mi][0], b[ni][0], acc[mi][ni], 0, 0, 0);
                acc[mi][ni] = __builtin_amdgcn_mfma_f32_16x16x32_bf16(
                    a[mi][1], b[ni][1], acc[mi][ni], 0, 0, 0);
            }
        __syncthreads();
    }
    float bias[4];
    #pragma unroll
    for (int ni = 0; ni < 4; ++ni) bias[ni] = bpv[n0 + 64 * wc + 16 * ni + lr];
    #pragma unroll
    for (int mi = 0; mi < 4; ++mi) {
        #pragma unroll
        for (int r = 0; r < 4; ++r) {
            const int m = m0 + 64 * wr + 16 * mi + 4 * lg + r;
            float* orow = out + (size_t)m * NC + n0 + 64 * wc;
            #pragma unroll
            for (int ni = 0; ni < 4; ++ni)
                orow[16 * ni + lr] = acc[mi][ni][r] + bias[ni];
        }
    }
}

extern "C" void kernel_launch(void* const* d_in, const int* in_sizes, int n_in,
                              void* d_out, int out_size, void* d_ws, size_t ws_size,
                              hipStream_t stream)
{
    const float* x  = (const float*)d_in[0];
    const float* Wq = (const float*)d_in[1];
    const float* Wk = (const float*)d_in[2];
    const float* Wv = (const float*)d_in[3];
    const float* Wp = (const float*)d_in[4];
    const float* bp = (const float*)d_in[5];

    float* out = (float*)d_out;                      // f32 outputs
    float* w = out + (size_t)NB * NT * NC;           // weights region (f32)

    ushort_t* xbf = (ushort_t*)d_ws;                             // 16.8 MB
    ushort_t* Wt  = xbf + (size_t)NB * NT * NC;                  // 6.3 MB
    ushort_t* qs  = Wt + (size_t)3 * NH * NHD * NC;              // 3 x 16.8 MB
    ushort_t* ks  = qs + (size_t)BH * NT * NHD;
    ushort_t* vs  = ks + (size_t)BH * NT * NHD;
    float* diag   = (float*)(vs + (size_t)BH * NT * NHD);        // 0.5 MB
    ushort_t* Wpb = (ushort_t*)(diag + (size_t)BH * NT);         // 2 MB
    ushort_t* vd  = Wpb + (size_t)NC * NC;                       // 16.8 MB

    cvt_x<<<(NB * NT * NC) / 1024, 256, 0, stream>>>(x, xbf);
    cvt_w<<<(3 * NH * NHD * NC) / 256, 256, 0, stream>>>(Wq, Wk, Wv, Wt);
    cvt_wp<<<(NC * NC) / 1024, 256, 0, stream>>>(Wp, Wpb);
    qkv_gemm2<<<dim3(24, 64), 256, 0, stream>>>(xbf, Wt, qs, ks, vs);
    scores_mfma<<<dim3(NT / 64, BH), 256, 0, stream>>>(qs, ks, w, diag);
    scale_v<<<(BH * NT * NHD) / (256 * 8), 256, 0, stream>>>(vs, diag, vd);
    out_gemm<<<dim3(8, 64), 256, 0, stream>>>(vd, Wpb, bp, out);
}